// Round 1
// baseline (319.672 us; speedup 1.0000x reference)
//
#include <hip/hip_runtime.h>
#include <math.h>
#include <stdint.h>
#include <stddef.h>

// Problem dims (fixed by the reference)
#define B_ROWS 4096
#define N_REAL 20000
#define NP     20096   // N padded to 157*128
#define D_IN   784
#define DP     800     // K padded to 25*32
#define NJT    157     // NP/128 column tiles in flash
#define NSPLIT 16      // N-dimension split for flash occupancy
#define LAMBD  0.05f
#define LN2    0.69314718055994530942f

typedef __attribute__((ext_vector_type(8))) short bf16x8;
typedef __attribute__((ext_vector_type(4))) float f32x4;

static __device__ __forceinline__ float bf2f(short s) {
  union { unsigned u; float f; } c;
  c.u = ((unsigned)(unsigned short)s) << 16;
  return c.f;
}
static __device__ __forceinline__ short f2bf(float f) {
  union { float f; unsigned u; } c;
  c.f = f;
  unsigned r = (c.u + 0x7fffu + ((c.u >> 16) & 1u)) >> 16;  // RNE
  return (short)(unsigned short)r;
}

// ---------------------------------------------------------------------------
// f32 -> bf16 convert with row/col zero-padding; optional exact f32 row sumsq.
// One block (256 thr) per padded row.
__global__ void k_convert(const float* __restrict__ src, short* __restrict__ dst,
                          float* __restrict__ sumsq, int rows, int colsSrc, int colsPad) {
  const int r = blockIdx.x;
  const int t = threadIdx.x;
  const bool realRow = r < rows;
  const float* sp = src + (size_t)r * colsSrc;
  short* dp = dst + (size_t)r * colsPad;
  float acc = 0.f;
  for (int c = t; c < colsPad; c += 256) {
    float v = (realRow && c < colsSrc) ? sp[c] : 0.f;
    dp[c] = f2bf(v);
    acc += v * v;
  }
  if (sumsq) {
    __shared__ float red[4];
    #pragma unroll
    for (int m = 1; m < 64; m <<= 1) acc += __shfl_xor(acc, m, 64);
    if ((t & 63) == 0) red[t >> 6] = acc;
    __syncthreads();
    if (t == 0) sumsq[r] = red[0] + red[1] + red[2] + red[3];
  }
}

// ---------------------------------------------------------------------------
// norm = mean(sy2[0:N_REAL]); scalars: [0]=norm [1]=1/norm [2]=c1
__global__ void k_norm(const float* __restrict__ sy2, float* __restrict__ scal) {
  __shared__ float red[16];
  const int t = threadIdx.x;  // 1024
  float a = 0.f;
  for (int j = t; j < N_REAL; j += 1024) a += sy2[j];
  #pragma unroll
  for (int m = 1; m < 64; m <<= 1) a += __shfl_xor(a, m, 64);
  if ((t & 63) == 0) red[t >> 6] = a;
  __syncthreads();
  if (t == 0) {
    float s = 0.f;
    for (int i = 0; i < 16; ++i) s += red[i];
    float norm = s / (float)N_REAL;
    scal[0] = norm;
    scal[1] = 1.0f / norm;
    scal[2] = 2.0f / (norm * LAMBD * LN2);  // c1: dot -> log2 exponent
  }
}

// ---------------------------------------------------------------------------
// C[M][Ncols](bf16) = act(A[M][K](bf16) * Bm[Ncols][K](bf16)^T + bias)
// 128x128 tile, 4 waves (2x2 of 64x64), K-step 32, double-buffered LDS.
__global__ __launch_bounds__(256) void k_gemm(const short* __restrict__ A,
                                              const short* __restrict__ Bm,
                                              const float* __restrict__ bias,
                                              short* __restrict__ C,
                                              int K, int Ncols, int relu) {
  __shared__ short Als[2][4096];
  __shared__ short Bls[2][4096];
  const int t = threadIdx.x;
  const int lane = t & 63, wave = t >> 6;
  const int lr = lane & 15, lg = lane >> 4;
  const int wrow = (wave >> 1) * 64, wcol = (wave & 1) * 64;
  const int rb = blockIdx.y, cb = blockIdx.x;
  const int srow = t >> 2, skoff = (t & 3) * 8;

  const short* Ag = A + (size_t)(rb * 128 + srow) * K + skoff;
  const short* Bg = Bm + (size_t)(cb * 128 + srow) * K + skoff;
  const size_t half = (size_t)64 * K;

  f32x4 acc[4][4];
  #pragma unroll
  for (int mi = 0; mi < 4; ++mi)
    #pragma unroll
    for (int ni = 0; ni < 4; ++ni)
      acc[mi][ni] = (f32x4){0.f, 0.f, 0.f, 0.f};

  // prologue: stage k-step 0 into buffer 0
  *(bf16x8*)&Als[0][t * 8]        = *(const bf16x8*)(Ag);
  *(bf16x8*)&Als[0][2048 + t * 8] = *(const bf16x8*)(Ag + half);
  *(bf16x8*)&Bls[0][t * 8]        = *(const bf16x8*)(Bg);
  *(bf16x8*)&Bls[0][2048 + t * 8] = *(const bf16x8*)(Bg + half);
  __syncthreads();

  const int KS = K >> 5;
  int cur = 0;
  for (int ks = 0; ks < KS; ++ks) {
    bf16x8 va0, va1, vb0, vb1;
    const bool more = (ks + 1 < KS);
    if (more) {
      const short* An = Ag + (ks + 1) * 32;
      const short* Bn = Bg + (ks + 1) * 32;
      va0 = *(const bf16x8*)(An);
      va1 = *(const bf16x8*)(An + half);
      vb0 = *(const bf16x8*)(Bn);
      vb1 = *(const bf16x8*)(Bn + half);
    }
    bf16x8 af[4], bfr[4];
    #pragma unroll
    for (int mi = 0; mi < 4; ++mi)
      af[mi] = *(const bf16x8*)&Als[cur][(wrow + mi * 16 + lr) * 32 + lg * 8];
    #pragma unroll
    for (int ni = 0; ni < 4; ++ni)
      bfr[ni] = *(const bf16x8*)&Bls[cur][(wcol + ni * 16 + lr) * 32 + lg * 8];
    #pragma unroll
    for (int mi = 0; mi < 4; ++mi)
      #pragma unroll
      for (int ni = 0; ni < 4; ++ni)
        acc[mi][ni] = __builtin_amdgcn_mfma_f32_16x16x32_bf16(af[mi], bfr[ni], acc[mi][ni], 0, 0, 0);
    if (more) {
      const int nb = cur ^ 1;
      *(bf16x8*)&Als[nb][t * 8]        = va0;
      *(bf16x8*)&Als[nb][2048 + t * 8] = va1;
      *(bf16x8*)&Bls[nb][t * 8]        = vb0;
      *(bf16x8*)&Bls[nb][2048 + t * 8] = vb1;
    }
    __syncthreads();
    cur ^= 1;
  }

  #pragma unroll
  for (int ni = 0; ni < 4; ++ni) {
    const int col = cb * 128 + wcol + ni * 16 + lr;
    const float bv = bias[col];
    #pragma unroll
    for (int mi = 0; mi < 4; ++mi) {
      const int row0 = rb * 128 + wrow + mi * 16 + lg * 4;
      #pragma unroll
      for (int r = 0; r < 4; ++r) {
        float v = acc[mi][ni][r] + bv;
        if (relu) v = fmaxf(v, 0.f);
        C[(size_t)(row0 + r) * Ncols + col] = f2bf(v);
      }
    }
  }
}

// ---------------------------------------------------------------------------
// psi[j] = H3[j,:128] . W3 + b3  (tiny final layer, f32 weights)
__global__ void k_l3(const short* __restrict__ H3, const float* __restrict__ W3,
                     const float* __restrict__ b3, float* __restrict__ psi) {
  const int j = blockIdx.x * 256 + threadIdx.x;
  if (j >= NP) return;
  const short* hp = H3 + (size_t)j * 128;
  float acc = 0.f;
  #pragma unroll
  for (int i = 0; i < 128; i += 8) {
    bf16x8 h = *(const bf16x8*)(hp + i);
    #pragma unroll
    for (int u = 0; u < 8; ++u) acc += bf2f(h[u]) * W3[i + u];
  }
  psi[j] = acc + b3[0];
}

// ---------------------------------------------------------------------------
// a2raw[j] = (psi - sy2/norm)/(lambda*ln2) + log2(nu);  block max + psi sum
__global__ void k_a2(const float* __restrict__ psi, const float* __restrict__ sy2,
                     const float* __restrict__ nu, const float* __restrict__ scal,
                     float* __restrict__ a2raw, float* __restrict__ maxp,
                     float* __restrict__ sump) {
  const int j = blockIdx.x * 256 + threadIdx.x;
  const float invn = scal[1];
  float a = -1e30f, p = 0.f;
  if (j < NP) {
    if (j < N_REAL) {
      p = psi[j];
      a = (p - sy2[j] * invn) * (1.0f / (LAMBD * LN2)) + log2f(nu[j]);
    }
    a2raw[j] = a;
  }
  __shared__ float redm[4], reds[4];
  #pragma unroll
  for (int m = 1; m < 64; m <<= 1) {
    a = fmaxf(a, __shfl_xor(a, m, 64));
    p += __shfl_xor(p, m, 64);
  }
  const int t = threadIdx.x;
  if ((t & 63) == 0) { redm[t >> 6] = a; reds[t >> 6] = p; }
  __syncthreads();
  if (t == 0) {
    maxp[blockIdx.x] = fmaxf(fmaxf(redm[0], redm[1]), fmaxf(redm[2], redm[3]));
    sump[blockIdx.x] = reds[0] + reds[1] + reds[2] + reds[3];
  }
}

__global__ void k_fin(const float* __restrict__ maxp, const float* __restrict__ sump,
                      float* __restrict__ scal, int nb) {
  const int t = threadIdx.x;  // 128
  __shared__ float ra[2], rs[2];
  float a = -1e30f, s = 0.f;
  for (int i = t; i < nb; i += 128) { a = fmaxf(a, maxp[i]); s += sump[i]; }
  #pragma unroll
  for (int m = 1; m < 64; m <<= 1) {
    a = fmaxf(a, __shfl_xor(a, m, 64));
    s += __shfl_xor(s, m, 64);
  }
  if ((t & 63) == 0) { ra[t >> 6] = a; rs[t >> 6] = s; }
  __syncthreads();
  if (t == 0) {
    scal[3] = fmaxf(ra[0], ra[1]);                 // A2 (global max, log2 domain)
    scal[4] = (rs[0] + rs[1]) / (float)N_REAL;     // mean(psi)
  }
}

__global__ void k_shift(float* __restrict__ a2s, const float* __restrict__ a2raw,
                        const float* __restrict__ scal) {
  const int j = blockIdx.x * 256 + threadIdx.x;
  if (j < NP) a2s[j] = a2raw[j] - scal[3];
}

// ---------------------------------------------------------------------------
// Fused flash LSE: per 128-row x-block, iterate y col-tiles (strided split),
// dot via MFMA, then sum exp2(dot*c1 + a2s[col]) into per-lane accumulators.
__global__ __launch_bounds__(256) void k_flash(const short* __restrict__ xb,
                                               const short* __restrict__ yb,
                                               const float* __restrict__ a2s,
                                               const float* __restrict__ scal,
                                               float* __restrict__ parts) {
  __shared__ short Als[2][4096];
  __shared__ short Bls[2][4096];
  const int t = threadIdx.x;
  const int lane = t & 63, wave = t >> 6;
  const int lr = lane & 15, lg = lane >> 4;
  const int wrow = (wave >> 1) * 64, wcol = (wave & 1) * 64;
  const int rb = blockIdx.y, split = blockIdx.x;
  const int srow = t >> 2, skoff = (t & 3) * 8;

  const short* Ag = xb + (size_t)(rb * 128 + srow) * DP + skoff;
  const size_t half = (size_t)64 * DP;
  const float c1 = scal[2];

  float sums[4][4];
  #pragma unroll
  for (int mi = 0; mi < 4; ++mi)
    #pragma unroll
    for (int r = 0; r < 4; ++r) sums[mi][r] = 0.f;

  for (int jt = split; jt < NJT; jt += NSPLIT) {
    const short* Bg = yb + (size_t)(jt * 128 + srow) * DP + skoff;
    f32x4 acc[4][4];
    #pragma unroll
    for (int mi = 0; mi < 4; ++mi)
      #pragma unroll
      for (int ni = 0; ni < 4; ++ni)
        acc[mi][ni] = (f32x4){0.f, 0.f, 0.f, 0.f};

    *(bf16x8*)&Als[0][t * 8]        = *(const bf16x8*)(Ag);
    *(bf16x8*)&Als[0][2048 + t * 8] = *(const bf16x8*)(Ag + half);
    *(bf16x8*)&Bls[0][t * 8]        = *(const bf16x8*)(Bg);
    *(bf16x8*)&Bls[0][2048 + t * 8] = *(const bf16x8*)(Bg + half);
    __syncthreads();

    int cur = 0;
    for (int ks = 0; ks < 25; ++ks) {   // DP/32
      bf16x8 va0, va1, vb0, vb1;
      const bool more = (ks + 1 < 25);
      if (more) {
        const short* An = Ag + (ks + 1) * 32;
        const short* Bn = Bg + (ks + 1) * 32;
        va0 = *(const bf16x8*)(An);
        va1 = *(const bf16x8*)(An + half);
        vb0 = *(const bf16x8*)(Bn);
        vb1 = *(const bf16x8*)(Bn + half);
      }
      bf16x8 af[4], bfr[4];
      #pragma unroll
      for (int mi = 0; mi < 4; ++mi)
        af[mi] = *(const bf16x8*)&Als[cur][(wrow + mi * 16 + lr) * 32 + lg * 8];
      #pragma unroll
      for (int ni = 0; ni < 4; ++ni)
        bfr[ni] = *(const bf16x8*)&Bls[cur][(wcol + ni * 16 + lr) * 32 + lg * 8];
      #pragma unroll
      for (int mi = 0; mi < 4; ++mi)
        #pragma unroll
        for (int ni = 0; ni < 4; ++ni)
          acc[mi][ni] = __builtin_amdgcn_mfma_f32_16x16x32_bf16(af[mi], bfr[ni], acc[mi][ni], 0, 0, 0);
      if (more) {
        const int nb = cur ^ 1;
        *(bf16x8*)&Als[nb][t * 8]        = va0;
        *(bf16x8*)&Als[nb][2048 + t * 8] = va1;
        *(bf16x8*)&Bls[nb][t * 8]        = vb0;
        *(bf16x8*)&Bls[nb][2048 + t * 8] = vb1;
      }
      __syncthreads();
      cur ^= 1;
    }

    // epilogue: sum exp2(dot*c1 + a2s[col]); registers only (no LDS hazard)
    #pragma unroll
    for (int ni = 0; ni < 4; ++ni) {
      const float av = a2s[jt * 128 + wcol + ni * 16 + lr];
      #pragma unroll
      for (int mi = 0; mi < 4; ++mi)
        #pragma unroll
        for (int r = 0; r < 4; ++r)
          sums[mi][r] += exp2f(acc[mi][ni][r] * c1 + av);
    }
  }

  // reduce each row's sum across the 16 lanes holding its columns
  #pragma unroll
  for (int mi = 0; mi < 4; ++mi)
    #pragma unroll
    for (int r = 0; r < 4; ++r) {
      float s = sums[mi][r];
      s += __shfl_xor(s, 1, 16);
      s += __shfl_xor(s, 2, 16);
      s += __shfl_xor(s, 4, 16);
      s += __shfl_xor(s, 8, 16);
      if (lr == 0) {
        const int row = rb * 128 + wrow + mi * 16 + lg * 4 + r;
        parts[(size_t)row * (2 * NSPLIT) + split * 2 + (wave & 1)] = s;
      }
    }
}

// ---------------------------------------------------------------------------
__global__ void k_comb(const float* __restrict__ parts, const float* __restrict__ x2,
                       const float* __restrict__ scal, float* __restrict__ out) {
  const int b = blockIdx.x * 256 + threadIdx.x;
  if (b >= B_ROWS) return;
  float s = 0.f;
  #pragma unroll
  for (int i = 0; i < 2 * NSPLIT; ++i) s += parts[(size_t)b * (2 * NSPLIT) + i];
  out[b] = -(LAMBD * LN2) * (scal[3] + log2f(s)) + x2[b] * scal[1] + scal[4];
}

// ---------------------------------------------------------------------------
extern "C" void kernel_launch(void* const* d_in, const int* in_sizes, int n_in,
                              void* d_out, int out_size, void* d_ws, size_t ws_size,
                              hipStream_t stream) {
  const float* x  = (const float*)d_in[0];
  const float* y  = (const float*)d_in[1];
  const float* nu = (const float*)d_in[2];
  const float* W0 = (const float*)d_in[3];
  const float* b0 = (const float*)d_in[4];
  const float* W1 = (const float*)d_in[5];
  const float* b1 = (const float*)d_in[6];
  const float* W2 = (const float*)d_in[7];
  const float* b2 = (const float*)d_in[8];
  const float* W3 = (const float*)d_in[9];
  const float* b3 = (const float*)d_in[10];
  float* out = (float*)d_out;

  char* w = (char*)d_ws;
  auto alloc = [&](size_t bytes) {
    char* p = w;
    w += (bytes + 255) & ~(size_t)255;
    return p;
  };
  short* y_bf  = (short*)alloc((size_t)NP * DP * 2);
  short* x_bf  = (short*)alloc((size_t)B_ROWS * DP * 2);
  short* W0b   = (short*)alloc((size_t)512 * DP * 2);
  short* W1b   = (short*)alloc((size_t)256 * 512 * 2);
  short* W2b   = (short*)alloc((size_t)128 * 256 * 2);
  short* H1    = (short*)alloc((size_t)NP * 512 * 2);
  short* H2    = (short*)alloc((size_t)NP * 256 * 2);
  short* H3    = (short*)alloc((size_t)NP * 128 * 2);
  float* sy2   = (float*)alloc((size_t)NP * 4);
  float* x2    = (float*)alloc((size_t)B_ROWS * 4);
  float* psi   = (float*)alloc((size_t)NP * 4);
  float* a2raw = (float*)alloc((size_t)NP * 4);
  float* a2s   = (float*)alloc((size_t)NP * 4);
  float* maxp  = (float*)alloc(128 * 4);
  float* sump  = (float*)alloc(128 * 4);
  float* scal  = (float*)alloc(64 * 4);
  float* parts = (float*)alloc((size_t)B_ROWS * 2 * NSPLIT * 4);

  // converts (+ exact f32 sumsq for y and x)
  k_convert<<<dim3(NP),     dim3(256), 0, stream>>>(y,  y_bf, sy2, N_REAL, D_IN, DP);
  k_convert<<<dim3(B_ROWS), dim3(256), 0, stream>>>(x,  x_bf, x2,  B_ROWS, D_IN, DP);
  k_convert<<<dim3(512),    dim3(256), 0, stream>>>(W0, W0b, nullptr, 512, D_IN, DP);
  k_convert<<<dim3(256),    dim3(256), 0, stream>>>(W1, W1b, nullptr, 256, 512, 512);
  k_convert<<<dim3(128),    dim3(256), 0, stream>>>(W2, W2b, nullptr, 128, 256, 256);
  k_norm<<<dim3(1), dim3(1024), 0, stream>>>(sy2, scal);

  // MLP
  k_gemm<<<dim3(4, NP / 128), dim3(256), 0, stream>>>(y_bf, W0b, b0, H1, DP,  512, 1);
  k_gemm<<<dim3(2, NP / 128), dim3(256), 0, stream>>>(H1,  W1b, b1, H2, 512, 256, 1);
  k_gemm<<<dim3(1, NP / 128), dim3(256), 0, stream>>>(H2,  W2b, b2, H3, 256, 128, 1);
  k_l3<<<dim3((NP + 255) / 256), dim3(256), 0, stream>>>(H3, W3, b3, psi);

  // a-vector + scalars
  const int nb_a2 = (NP + 255) / 256;
  k_a2<<<dim3(nb_a2), dim3(256), 0, stream>>>(psi, sy2, nu, scal, a2raw, maxp, sump);
  k_fin<<<dim3(1), dim3(128), 0, stream>>>(maxp, sump, scal, nb_a2);
  k_shift<<<dim3(nb_a2), dim3(256), 0, stream>>>(a2s, a2raw, scal);

  // fused flash LSE + combine
  k_flash<<<dim3(NSPLIT, B_ROWS / 128), dim3(256), 0, stream>>>(x_bf, y_bf, a2s, scal, parts);
  k_comb<<<dim3(B_ROWS / 256), dim3(256), 0, stream>>>(parts, x2, scal, out);
}

// Round 2
// 263.222 us; speedup vs baseline: 1.2145x; 1.2145x over previous
//
#include <hip/hip_runtime.h>
#include <math.h>
#include <stdint.h>
#include <stddef.h>

// Problem dims (fixed by the reference)
#define B_ROWS 4096
#define N_REAL 20000
#define NP     20096   // N padded to 157*128
#define D_IN   784
#define DP     800     // K padded to 25*32
#define KS_D   25      // DP/32 k-steps
#define NJT    157     // NP/128 column tiles in flash
#define NXT    32      // B_ROWS/128 row tiles
#define NSPLIT 32      // N-dimension split for flash occupancy
#define LAMBD  0.05f
#define LN2    0.69314718055994530942f

typedef __attribute__((ext_vector_type(8))) short bf16x8;
typedef __attribute__((ext_vector_type(4))) float f32x4;

typedef const unsigned int __attribute__((address_space(1)))* gas_u32p;
typedef unsigned int __attribute__((address_space(3)))* las_u32p;

static __device__ __forceinline__ void gload_lds16(const short* g, short* l) {
  // dest = wave-uniform LDS base + lane*16B; source is per-lane
  __builtin_amdgcn_global_load_lds((gas_u32p)(const void*)g, (las_u32p)(void*)l, 16, 0, 0);
}

static __device__ __forceinline__ float bf2f(short s) {
  union { unsigned u; float f; } c;
  c.u = ((unsigned)(unsigned short)s) << 16;
  return c.f;
}
static __device__ __forceinline__ short f2bf(float f) {
  union { float f; unsigned u; } c;
  c.f = f;
  unsigned r = (c.u + 0x7fffu + ((c.u >> 16) & 1u)) >> 16;  // RNE
  return (short)(unsigned short)r;
}

// ---------------------------------------------------------------------------
// Exact f32 row sum-of-squares (reads original f32 data).
__global__ void k_sumsq(const float* __restrict__ src, float* __restrict__ out, int cols4) {
  const int r = blockIdx.x, t = threadIdx.x;
  const float4* sp = (const float4*)(src + (size_t)r * (cols4 * 4));
  float acc = 0.f;
  for (int c = t; c < cols4; c += 256) {
    float4 v = sp[c];
    acc += v.x * v.x + v.y * v.y + v.z * v.z + v.w * v.w;
  }
  __shared__ float red[4];
  #pragma unroll
  for (int m = 1; m < 64; m <<= 1) acc += __shfl_xor(acc, m, 64);
  if ((t & 63) == 0) red[t >> 6] = acc;
  __syncthreads();
  if (t == 0) out[r] = red[0] + red[1] + red[2] + red[3];
}

// ---------------------------------------------------------------------------
// f32 -> bf16 TILED convert: out[tile][ks][kc][row=128][8] ; each (tile,ks)
// 8KB block is the exact LDS image of a 128x32 K-step tile (conflict-free
// reads + linear global_load_lds staging). Block per (tile,ks).
__global__ void k_convt(const float* __restrict__ src, short* __restrict__ dst,
                        int rows, int cols /*784*/) {
  const int tile = blockIdx.x / KS_D, ks = blockIdx.x % KS_D;
  const int t = threadIdx.x;
  const int row = t >> 1, half = t & 1;
  const int r = tile * 128 + row;
  const int c0 = ks * 32 + half * 16;
  float v[16];
  if (r < rows && c0 < cols) {   // cols % 16 == 0 -> chunk fully in or out
    const float4* sp = (const float4*)(src + (size_t)r * cols + c0);
    #pragma unroll
    for (int q = 0; q < 4; ++q) {
      float4 u = sp[q];
      v[q * 4 + 0] = u.x; v[q * 4 + 1] = u.y; v[q * 4 + 2] = u.z; v[q * 4 + 3] = u.w;
    }
  } else {
    #pragma unroll
    for (int q = 0; q < 16; ++q) v[q] = 0.f;
  }
  bf16x8 o0, o1;
  #pragma unroll
  for (int q = 0; q < 8; ++q) { o0[q] = f2bf(v[q]); o1[q] = f2bf(v[8 + q]); }
  short* dp = dst + (size_t)blockIdx.x * 4096 + ((size_t)(half * 2) * 128 + row) * 8;
  *(bf16x8*)dp = o0;
  *(bf16x8*)(dp + 1024) = o1;   // kc+1 plane
}

// ---------------------------------------------------------------------------
// Row-major f32 -> bf16 with zero pad (weights only).
__global__ void k_convert(const float* __restrict__ src, short* __restrict__ dst,
                          int rows, int colsSrc, int colsPad) {
  const int r = blockIdx.x;
  const int t = threadIdx.x;
  const float* sp = src + (size_t)r * colsSrc;
  short* dp = dst + (size_t)r * colsPad;
  for (int c = t; c < colsPad; c += 256)
    dp[c] = f2bf(c < colsSrc ? sp[c] : 0.f);
}

// ---------------------------------------------------------------------------
// norm = mean(sy2[0:N_REAL]); scalars: [0]=norm [1]=1/norm [2]=c1
__global__ void k_norm(const float* __restrict__ sy2, float* __restrict__ scal) {
  __shared__ float red[16];
  const int t = threadIdx.x;  // 1024
  float a = 0.f;
  for (int j = t; j < N_REAL; j += 1024) a += sy2[j];
  #pragma unroll
  for (int m = 1; m < 64; m <<= 1) a += __shfl_xor(a, m, 64);
  if ((t & 63) == 0) red[t >> 6] = a;
  __syncthreads();
  if (t == 0) {
    float s = 0.f;
    for (int i = 0; i < 16; ++i) s += red[i];
    float norm = s / (float)N_REAL;
    scal[0] = norm;
    scal[1] = 1.0f / norm;
    scal[2] = 2.0f / (norm * LAMBD * LN2);  // c1: dot -> log2 exponent
  }
}

// ---------------------------------------------------------------------------
// C[M][Ncols](bf16) = act(A * Bm^T + bias). A row-major [M][K] or TILED
// (k_convt layout). Bm row-major [Ncols][K]. 128x128 tile, 4 waves.
template <bool TA>
__global__ __launch_bounds__(256) void k_gemm(const short* __restrict__ A,
                                              const short* __restrict__ Bm,
                                              const float* __restrict__ bias,
                                              short* __restrict__ C,
                                              int K, int Ncols, int relu) {
  __shared__ short Als[2][4096];
  __shared__ short Bls[2][4096];
  const int t = threadIdx.x;
  const int lane = t & 63, wave = t >> 6;
  const int lr = lane & 15, lg = lane >> 4;
  const int wrow = (wave >> 1) * 64, wcol = (wave & 1) * 64;
  const int rb = blockIdx.y, cb = blockIdx.x;
  const int srow = t >> 2, skoff = (t & 3) * 8;
  const int KS = K >> 5;

  const short* Ag  = A + (size_t)(rb * 128 + srow) * K + skoff;
  const short* AgT = A + (size_t)rb * KS * 4096 + (size_t)(t & 3) * 1024 + (size_t)srow * 8;
  const short* Bg  = Bm + (size_t)(cb * 128 + srow) * K + skoff;
  const size_t halfA = (size_t)64 * K;

  auto a_chunk = [&](int ks, int h) -> const short* {
    if constexpr (TA) return AgT + (size_t)ks * 4096 + h * 512;
    else              return Ag + ks * 32 + (h ? halfA : 0);
  };

  f32x4 acc[4][4];
  #pragma unroll
  for (int mi = 0; mi < 4; ++mi)
    #pragma unroll
    for (int ni = 0; ni < 4; ++ni)
      acc[mi][ni] = (f32x4){0.f, 0.f, 0.f, 0.f};

  *(bf16x8*)&Als[0][t * 8]        = *(const bf16x8*)a_chunk(0, 0);
  *(bf16x8*)&Als[0][2048 + t * 8] = *(const bf16x8*)a_chunk(0, 1);
  *(bf16x8*)&Bls[0][t * 8]        = *(const bf16x8*)(Bg);
  *(bf16x8*)&Bls[0][2048 + t * 8] = *(const bf16x8*)(Bg + halfA);
  __syncthreads();

  int cur = 0;
  for (int ks = 0; ks < KS; ++ks) {
    bf16x8 va0, va1, vb0, vb1;
    const bool more = (ks + 1 < KS);
    if (more) {
      va0 = *(const bf16x8*)a_chunk(ks + 1, 0);
      va1 = *(const bf16x8*)a_chunk(ks + 1, 1);
      const short* Bn = Bg + (ks + 1) * 32;
      vb0 = *(const bf16x8*)(Bn);
      vb1 = *(const bf16x8*)(Bn + halfA);
    }
    bf16x8 af[4], bfr[4];
    #pragma unroll
    for (int mi = 0; mi < 4; ++mi)
      af[mi] = *(const bf16x8*)&Als[cur][(wrow + mi * 16 + lr) * 32 + lg * 8];
    #pragma unroll
    for (int ni = 0; ni < 4; ++ni)
      bfr[ni] = *(const bf16x8*)&Bls[cur][(wcol + ni * 16 + lr) * 32 + lg * 8];
    #pragma unroll
    for (int mi = 0; mi < 4; ++mi)
      #pragma unroll
      for (int ni = 0; ni < 4; ++ni)
        acc[mi][ni] = __builtin_amdgcn_mfma_f32_16x16x32_bf16(af[mi], bfr[ni], acc[mi][ni], 0, 0, 0);
    if (more) {
      const int nb = cur ^ 1;
      *(bf16x8*)&Als[nb][t * 8]        = va0;
      *(bf16x8*)&Als[nb][2048 + t * 8] = va1;
      *(bf16x8*)&Bls[nb][t * 8]        = vb0;
      *(bf16x8*)&Bls[nb][2048 + t * 8] = vb1;
    }
    __syncthreads();
    cur ^= 1;
  }

  #pragma unroll
  for (int ni = 0; ni < 4; ++ni) {
    const int col = cb * 128 + wcol + ni * 16 + lr;
    const float bv = bias[col];
    #pragma unroll
    for (int mi = 0; mi < 4; ++mi) {
      const int row0 = rb * 128 + wrow + mi * 16 + lg * 4;
      #pragma unroll
      for (int r = 0; r < 4; ++r) {
        float v = acc[mi][ni][r] + bv;
        if (relu) v = fmaxf(v, 0.f);
        C[(size_t)(row0 + r) * Ncols + col] = f2bf(v);
      }
    }
  }
}

// ---------------------------------------------------------------------------
// psi[j] = H3[j,:128] . W3 + b3
__global__ void k_l3(const short* __restrict__ H3, const float* __restrict__ W3,
                     const float* __restrict__ b3, float* __restrict__ psi) {
  const int j = blockIdx.x * 256 + threadIdx.x;
  if (j >= NP) return;
  const short* hp = H3 + (size_t)j * 128;
  float acc = 0.f;
  #pragma unroll
  for (int i = 0; i < 128; i += 8) {
    bf16x8 h = *(const bf16x8*)(hp + i);
    #pragma unroll
    for (int u = 0; u < 8; ++u) acc += bf2f(h[u]) * W3[i + u];
  }
  psi[j] = acc + b3[0];
}

// ---------------------------------------------------------------------------
// a2raw[j] = (psi - sy2/norm)/(lambda*ln2) + log2(nu);  block max + psi sum
__global__ void k_a2(const float* __restrict__ psi, const float* __restrict__ sy2,
                     const float* __restrict__ nu, const float* __restrict__ scal,
                     float* __restrict__ a2raw, float* __restrict__ maxp,
                     float* __restrict__ sump) {
  const int j = blockIdx.x * 256 + threadIdx.x;
  const float invn = scal[1];
  float a = -1e30f, p = 0.f;
  if (j < NP) {
    if (j < N_REAL) {
      p = psi[j];
      a = (p - sy2[j] * invn) * (1.0f / (LAMBD * LN2)) + log2f(nu[j]);
    }
    a2raw[j] = a;
  }
  __shared__ float redm[4], reds[4];
  #pragma unroll
  for (int m = 1; m < 64; m <<= 1) {
    a = fmaxf(a, __shfl_xor(a, m, 64));
    p += __shfl_xor(p, m, 64);
  }
  const int t = threadIdx.x;
  if ((t & 63) == 0) { redm[t >> 6] = a; reds[t >> 6] = p; }
  __syncthreads();
  if (t == 0) {
    maxp[blockIdx.x] = fmaxf(fmaxf(redm[0], redm[1]), fmaxf(redm[2], redm[3]));
    sump[blockIdx.x] = reds[0] + reds[1] + reds[2] + reds[3];
  }
}

__global__ void k_fin(const float* __restrict__ maxp, const float* __restrict__ sump,
                      float* __restrict__ scal, int nb) {
  const int t = threadIdx.x;  // 128
  __shared__ float ra[2], rs[2];
  float a = -1e30f, s = 0.f;
  for (int i = t; i < nb; i += 128) { a = fmaxf(a, maxp[i]); s += sump[i]; }
  #pragma unroll
  for (int m = 1; m < 64; m <<= 1) {
    a = fmaxf(a, __shfl_xor(a, m, 64));
    s += __shfl_xor(s, m, 64);
  }
  if ((t & 63) == 0) { ra[t >> 6] = a; rs[t >> 6] = s; }
  __syncthreads();
  if (t == 0) {
    scal[3] = fmaxf(ra[0], ra[1]);                 // A2 (global max, log2 domain)
    scal[4] = (rs[0] + rs[1]) / (float)N_REAL;     // mean(psi)
  }
}

__global__ void k_shift(float* __restrict__ a2s, const float* __restrict__ a2raw,
                        const float* __restrict__ scal) {
  const int j = blockIdx.x * 256 + threadIdx.x;
  if (j < NP) a2s[j] = a2raw[j] - scal[3];
}

// ---------------------------------------------------------------------------
// Fused flash LSE over tiled operands. Staging = linear 8KB copies via
// global_load_lds width 16; LDS image [kc=4][row=128][8] -> conflict-free
// ds_read_b128 fragment reads.
__global__ __launch_bounds__(256, 4) void k_flash(const short* __restrict__ x_t,
                                                  const short* __restrict__ y_t,
                                                  const float* __restrict__ a2s,
                                                  const float* __restrict__ scal,
                                                  float* __restrict__ parts) {
  __shared__ short L[2][2][4096];   // [buf][A=0/B=1][4*128*8] = 32 KB
  const int t = threadIdx.x;
  const int lane = t & 63, wave = t >> 6;
  const int lr = lane & 15, lg = lane >> 4;
  const int wrow = (wave >> 1) * 64, wcol = (wave & 1) * 64;
  const int rb = blockIdx.y, split = blockIdx.x;
  const float c1 = scal[2];

  const int soff = wave * 1024 + lane * 8;   // per-lane source offset (shorts)
  const int ldsoff = wave * 1024;            // wave-uniform LDS offset (shorts)
  const short* Abase = x_t + (size_t)rb * (KS_D * 4096);

  auto stage = [&](int buf, int ks, int jt) {
    const short* as = Abase + (size_t)ks * 4096 + soff;
    const short* bs = y_t + ((size_t)jt * KS_D + ks) * 4096 + soff;
    gload_lds16(as,       &L[buf][0][ldsoff]);
    gload_lds16(as + 512, &L[buf][0][ldsoff + 512]);
    gload_lds16(bs,       &L[buf][1][ldsoff]);
    gload_lds16(bs + 512, &L[buf][1][ldsoff + 512]);
  };

  float sums[4][4];
  #pragma unroll
  for (int mi = 0; mi < 4; ++mi)
    #pragma unroll
    for (int r = 0; r < 4; ++r) sums[mi][r] = 0.f;

  stage(0, 0, split);
  __syncthreads();
  int cur = 0;

  for (int jt = split; jt < NJT; jt += NSPLIT) {
    f32x4 acc[4][4];
    #pragma unroll
    for (int mi = 0; mi < 4; ++mi)
      #pragma unroll
      for (int ni = 0; ni < 4; ++ni)
        acc[mi][ni] = (f32x4){0.f, 0.f, 0.f, 0.f};

    for (int ks = 0; ks < KS_D; ++ks) {
      // issue next stage (async) before consuming current buffer
      int sjt = jt, sks = ks + 1;
      bool more = true;
      if (sks == KS_D) { sjt = jt + NSPLIT; sks = 0; more = (sjt < NJT); }
      if (more) stage(cur ^ 1, sks, sjt);

      bf16x8 af[4], bfr[4];
      #pragma unroll
      for (int mi = 0; mi < 4; ++mi)
        af[mi] = *(const bf16x8*)&L[cur][0][(lg * 128 + wrow + mi * 16 + lr) * 8];
      #pragma unroll
      for (int ni = 0; ni < 4; ++ni)
        bfr[ni] = *(const bf16x8*)&L[cur][1][(lg * 128 + wcol + ni * 16 + lr) * 8];
      #pragma unroll
      for (int mi = 0; mi < 4; ++mi)
        #pragma unroll
        for (int ni = 0; ni < 4; ++ni)
          acc[mi][ni] = __builtin_amdgcn_mfma_f32_16x16x32_bf16(af[mi], bfr[ni], acc[mi][ni], 0, 0, 0);
      __syncthreads();   // drains this step's async loads; next buffer ready
      cur ^= 1;
    }

    // epilogue: sums += exp2(dot*c1 + a2s[col]); registers only
    #pragma unroll
    for (int ni = 0; ni < 4; ++ni) {
      const float av = a2s[jt * 128 + wcol + ni * 16 + lr];
      #pragma unroll
      for (int mi = 0; mi < 4; ++mi)
        #pragma unroll
        for (int r = 0; r < 4; ++r)
          sums[mi][r] += exp2f(acc[mi][ni][r] * c1 + av);
    }
  }

  // reduce each row's sum across the 16 lanes holding its columns
  #pragma unroll
  for (int mi = 0; mi < 4; ++mi)
    #pragma unroll
    for (int r = 0; r < 4; ++r) {
      float s = sums[mi][r];
      s += __shfl_xor(s, 1, 16);
      s += __shfl_xor(s, 2, 16);
      s += __shfl_xor(s, 4, 16);
      s += __shfl_xor(s, 8, 16);
      if (lr == 0) {
        const int row = rb * 128 + wrow + mi * 16 + lg * 4 + r;
        parts[(size_t)row * (2 * NSPLIT) + split * 2 + (wave & 1)] = s;
      }
    }
}

// ---------------------------------------------------------------------------
__global__ void k_comb(const float* __restrict__ parts, const float* __restrict__ x2,
                       const float* __restrict__ scal, float* __restrict__ out) {
  const int b = blockIdx.x * 256 + threadIdx.x;
  if (b >= B_ROWS) return;
  float s = 0.f;
  #pragma unroll
  for (int i = 0; i < 2 * NSPLIT; ++i) s += parts[(size_t)b * (2 * NSPLIT) + i];
  out[b] = -(LAMBD * LN2) * (scal[3] + log2f(s)) + x2[b] * scal[1] + scal[4];
}

// ---------------------------------------------------------------------------
extern "C" void kernel_launch(void* const* d_in, const int* in_sizes, int n_in,
                              void* d_out, int out_size, void* d_ws, size_t ws_size,
                              hipStream_t stream) {
  const float* x  = (const float*)d_in[0];
  const float* y  = (const float*)d_in[1];
  const float* nu = (const float*)d_in[2];
  const float* W0 = (const float*)d_in[3];
  const float* b0 = (const float*)d_in[4];
  const float* W1 = (const float*)d_in[5];
  const float* b1 = (const float*)d_in[6];
  const float* W2 = (const float*)d_in[7];
  const float* b2 = (const float*)d_in[8];
  const float* W3 = (const float*)d_in[9];
  const float* b3 = (const float*)d_in[10];
  float* out = (float*)d_out;

  char* w = (char*)d_ws;
  auto alloc = [&](size_t bytes) {
    char* p = w;
    w += (bytes + 255) & ~(size_t)255;
    return p;
  };
  short* y_t   = (short*)alloc((size_t)NJT * KS_D * 4096 * 2);   // tiled y
  short* x_t   = (short*)alloc((size_t)NXT * KS_D * 4096 * 2);   // tiled x
  short* W0b   = (short*)alloc((size_t)512 * DP * 2);
  short* W1b   = (short*)alloc((size_t)256 * 512 * 2);
  short* W2b   = (short*)alloc((size_t)128 * 256 * 2);
  short* H1    = (short*)alloc((size_t)NP * 512 * 2);
  short* H2    = (short*)alloc((size_t)NP * 256 * 2);
  short* H3    = (short*)alloc((size_t)NP * 128 * 2);
  float* sy2   = (float*)alloc((size_t)N_REAL * 4);
  float* x2    = (float*)alloc((size_t)B_ROWS * 4);
  float* psi   = (float*)alloc((size_t)NP * 4);
  float* a2raw = (float*)alloc((size_t)NP * 4);
  float* a2s   = (float*)alloc((size_t)NP * 4);
  float* maxp  = (float*)alloc(128 * 4);
  float* sump  = (float*)alloc(128 * 4);
  float* scal  = (float*)alloc(64 * 4);
  float* parts = (float*)alloc((size_t)B_ROWS * 2 * NSPLIT * 4);

  // exact f32 row sumsq from original data
  k_sumsq<<<dim3(N_REAL), dim3(256), 0, stream>>>(y, sy2, D_IN / 4);
  k_sumsq<<<dim3(B_ROWS), dim3(256), 0, stream>>>(x, x2, D_IN / 4);
  k_norm<<<dim3(1), dim3(1024), 0, stream>>>(sy2, scal);

  // tiled bf16 operands + row-major weights
  k_convt<<<dim3(NJT * KS_D), dim3(256), 0, stream>>>(y, y_t, N_REAL, D_IN);
  k_convt<<<dim3(NXT * KS_D), dim3(256), 0, stream>>>(x, x_t, B_ROWS, D_IN);
  k_convert<<<dim3(512), dim3(256), 0, stream>>>(W0, W0b, 512, D_IN, DP);
  k_convert<<<dim3(256), dim3(256), 0, stream>>>(W1, W1b, 256, 512, 512);
  k_convert<<<dim3(128), dim3(256), 0, stream>>>(W2, W2b, 128, 256, 256);

  // MLP (layer 0 reads tiled y)
  k_gemm<true><<<dim3(4, NP / 128), dim3(256), 0, stream>>>(y_t, W0b, b0, H1, DP,  512, 1);
  k_gemm<false><<<dim3(2, NP / 128), dim3(256), 0, stream>>>(H1, W1b, b1, H2, 512, 256, 1);
  k_gemm<false><<<dim3(1, NP / 128), dim3(256), 0, stream>>>(H2, W2b, b2, H3, 256, 128, 1);
  k_l3<<<dim3((NP + 255) / 256), dim3(256), 0, stream>>>(H3, W3, b3, psi);

  // a-vector + scalars
  const int nb_a2 = (NP + 255) / 256;
  k_a2<<<dim3(nb_a2), dim3(256), 0, stream>>>(psi, sy2, nu, scal, a2raw, maxp, sump);
  k_fin<<<dim3(1), dim3(128), 0, stream>>>(maxp, sump, scal, nb_a2);
  k_shift<<<dim3(nb_a2), dim3(256), 0, stream>>>(a2s, a2raw, scal);

  // fused flash LSE + combine
  k_flash<<<dim3(NSPLIT, B_ROWS / 128), dim3(256), 0, stream>>>(x_t, y_t, a2s, scal, parts);
  k_comb<<<dim3(B_ROWS / 256), dim3(256), 0, stream>>>(parts, x2, scal, out);
}

// Round 3
// 247.522 us; speedup vs baseline: 1.2915x; 1.0634x over previous
//
#include <hip/hip_runtime.h>
#include <math.h>
#include <stdint.h>
#include <stddef.h>

// Problem dims (fixed by the reference)
#define B_ROWS 4096
#define N_REAL 20000
#define NP2    20224   // N padded to 79*256
#define NJT2   79      // 256-col y tiles
#define D_IN   784
#define DP2    832     // K padded to 13*64
#define NKT    13      // K-tiles of 64
#define NSPLIT2 16     // N-split for flash (grid = 16 x 16 = 256 blocks)
#define LAMBD  0.05f
#define LN2    0.69314718055994530942f

typedef __attribute__((ext_vector_type(8))) short bf16x8;
typedef __attribute__((ext_vector_type(4))) float f32x4;

typedef const unsigned int __attribute__((address_space(1)))* gas_u32p;
typedef unsigned int __attribute__((address_space(3)))* las_u32p;

static __device__ __forceinline__ void gload_lds16(const short* g, short* l) {
  // dest = wave-uniform LDS base + lane*16B; source is per-lane
  __builtin_amdgcn_global_load_lds((gas_u32p)(const void*)g, (las_u32p)(void*)l, 16, 0, 0);
}

static __device__ __forceinline__ float bf2f(short s) {
  union { unsigned u; float f; } c;
  c.u = ((unsigned)(unsigned short)s) << 16;
  return c.f;
}
static __device__ __forceinline__ short f2bf(float f) {
  union { float f; unsigned u; } c;
  c.f = f;
  unsigned r = (c.u + 0x7fffu + ((c.u >> 16) & 1u)) >> 16;  // RNE
  return (short)(unsigned short)r;
}

// ---------------------------------------------------------------------------
// Exact f32 row sum-of-squares (reads original f32 data).
__global__ void k_sumsq(const float* __restrict__ src, float* __restrict__ out, int cols4) {
  const int r = blockIdx.x, t = threadIdx.x;
  const float4* sp = (const float4*)(src + (size_t)r * (cols4 * 4));
  float acc = 0.f;
  for (int c = t; c < cols4; c += 256) {
    float4 v = sp[c];
    acc += v.x * v.x + v.y * v.y + v.z * v.z + v.w * v.w;
  }
  __shared__ float red[4];
  #pragma unroll
  for (int m = 1; m < 64; m <<= 1) acc += __shfl_xor(acc, m, 64);
  if ((t & 63) == 0) red[t >> 6] = acc;
  __syncthreads();
  if (t == 0) out[r] = red[0] + red[1] + red[2] + red[3];
}

// ---------------------------------------------------------------------------
// f32 -> bf16 TILED convert into 256-row K-tile images:
// dst[(tile*13 + kt)*16384 + (kc*256 + row)*8 + e] = src[tile*256+row][kt*64+kc*8+e]
// Each (tile,kt) image is 32KB, the exact LDS image for flash staging.
__global__ void k_convt(const float* __restrict__ src, short* __restrict__ dst,
                        int rows) {
  const int tile = blockIdx.x / NKT, kt = blockIdx.x % NKT;
  const int t = threadIdx.x;           // row within 256-tile
  const int r = tile * 256 + t;
  const int c0 = kt * 64;
  float v[64];
  if (r < rows) {
    const float* sp = src + (size_t)r * D_IN;
    #pragma unroll
    for (int q = 0; q < 16; ++q) {
      const int c = c0 + q * 4;
      float4 u = (c < D_IN) ? *(const float4*)(sp + c) : make_float4(0.f, 0.f, 0.f, 0.f);
      v[q * 4 + 0] = u.x; v[q * 4 + 1] = u.y; v[q * 4 + 2] = u.z; v[q * 4 + 3] = u.w;
    }
  } else {
    #pragma unroll
    for (int q = 0; q < 64; ++q) v[q] = 0.f;
  }
  short* dp = dst + (size_t)blockIdx.x * 16384;
  #pragma unroll
  for (int kc = 0; kc < 8; ++kc) {
    bf16x8 o;
    #pragma unroll
    for (int e = 0; e < 8; ++e) o[e] = f2bf(v[kc * 8 + e]);
    *(bf16x8*)(dp + ((size_t)kc * 256 + t) * 8) = o;
  }
}

// ---------------------------------------------------------------------------
// Row-major f32 -> bf16 with zero pad (weights only).
__global__ void k_convert(const float* __restrict__ src, short* __restrict__ dst,
                          int rows, int colsSrc, int colsPad) {
  const int r = blockIdx.x;
  const int t = threadIdx.x;
  const float* sp = src + (size_t)r * colsSrc;
  short* dp = dst + (size_t)r * colsPad;
  for (int c = t; c < colsPad; c += 256)
    dp[c] = f2bf(c < colsSrc ? sp[c] : 0.f);
}

// ---------------------------------------------------------------------------
// norm = mean(sy2[0:N_REAL]); scalars: [0]=norm [1]=1/norm [2]=c1
__global__ void k_norm(const float* __restrict__ sy2, float* __restrict__ scal) {
  __shared__ float red[16];
  const int t = threadIdx.x;  // 1024
  float a = 0.f;
  for (int j = t; j < N_REAL; j += 1024) a += sy2[j];
  #pragma unroll
  for (int m = 1; m < 64; m <<= 1) a += __shfl_xor(a, m, 64);
  if ((t & 63) == 0) red[t >> 6] = a;
  __syncthreads();
  if (t == 0) {
    float s = 0.f;
    for (int i = 0; i < 16; ++i) s += red[i];
    float norm = s / (float)N_REAL;
    scal[0] = norm;
    scal[1] = 1.0f / norm;
    scal[2] = 2.0f / (norm * LAMBD * LN2);  // c1: dot -> log2 exponent
  }
}

// ---------------------------------------------------------------------------
// C[M][Ncols](bf16) = act(A * Bm^T + bias). A row-major [M][K] or TILED
// (k_convt 256-row image layout). Bm row-major [Ncols][K]. 128x128 tile.
template <bool TA>
__global__ __launch_bounds__(256) void k_gemm(const short* __restrict__ A,
                                              const short* __restrict__ Bm,
                                              const float* __restrict__ bias,
                                              short* __restrict__ C,
                                              int K, int Ncols, int relu) {
  __shared__ short Als[2][4096];
  __shared__ short Bls[2][4096];
  const int t = threadIdx.x;
  const int lane = t & 63, wave = t >> 6;
  const int lr = lane & 15, lg = lane >> 4;
  const int wrow = (wave >> 1) * 64, wcol = (wave & 1) * 64;
  const int rb = blockIdx.y, cb = blockIdx.x;
  const int srow = t >> 2, skoff = (t & 3) * 8;
  const int KS = K >> 5;

  const short* Ag  = A + (size_t)(rb * 128 + srow) * K + skoff;
  const short* Bg  = Bm + (size_t)(cb * 128 + srow) * K + skoff;
  const size_t halfA = (size_t)64 * K;

  auto a_chunk = [&](int ks, int h) -> const short* {
    if constexpr (TA) {
      // tiled image: [(rb>>1)*13 + kt][kc*256 + row]*8
      return A + ((size_t)((rb >> 1) * NKT + (ks >> 1)) << 14)
               + ((size_t)((((ks & 1) * 4 + (t & 3)) << 8) + (rb & 1) * 128 + h * 64 + srow) << 3);
    } else {
      return Ag + ks * 32 + (h ? halfA : 0);
    }
  };

  f32x4 acc[4][4];
  #pragma unroll
  for (int mi = 0; mi < 4; ++mi)
    #pragma unroll
    for (int ni = 0; ni < 4; ++ni)
      acc[mi][ni] = (f32x4){0.f, 0.f, 0.f, 0.f};

  *(bf16x8*)&Als[0][t * 8]        = *(const bf16x8*)a_chunk(0, 0);
  *(bf16x8*)&Als[0][2048 + t * 8] = *(const bf16x8*)a_chunk(0, 1);
  *(bf16x8*)&Bls[0][t * 8]        = *(const bf16x8*)(Bg);
  *(bf16x8*)&Bls[0][2048 + t * 8] = *(const bf16x8*)(Bg + halfA);
  __syncthreads();

  int cur = 0;
  for (int ks = 0; ks < KS; ++ks) {
    bf16x8 va0, va1, vb0, vb1;
    const bool more = (ks + 1 < KS);
    if (more) {
      va0 = *(const bf16x8*)a_chunk(ks + 1, 0);
      va1 = *(const bf16x8*)a_chunk(ks + 1, 1);
      const short* Bn = Bg + (ks + 1) * 32;
      vb0 = *(const bf16x8*)(Bn);
      vb1 = *(const bf16x8*)(Bn + halfA);
    }
    bf16x8 af[4], bfr[4];
    #pragma unroll
    for (int mi = 0; mi < 4; ++mi)
      af[mi] = *(const bf16x8*)&Als[cur][(wrow + mi * 16 + lr) * 32 + lg * 8];
    #pragma unroll
    for (int ni = 0; ni < 4; ++ni)
      bfr[ni] = *(const bf16x8*)&Bls[cur][(wcol + ni * 16 + lr) * 32 + lg * 8];
    #pragma unroll
    for (int mi = 0; mi < 4; ++mi)
      #pragma unroll
      for (int ni = 0; ni < 4; ++ni)
        acc[mi][ni] = __builtin_amdgcn_mfma_f32_16x16x32_bf16(af[mi], bfr[ni], acc[mi][ni], 0, 0, 0);
    if (more) {
      const int nb = cur ^ 1;
      *(bf16x8*)&Als[nb][t * 8]        = va0;
      *(bf16x8*)&Als[nb][2048 + t * 8] = va1;
      *(bf16x8*)&Bls[nb][t * 8]        = vb0;
      *(bf16x8*)&Bls[nb][2048 + t * 8] = vb1;
    }
    __syncthreads();
    cur ^= 1;
  }

  #pragma unroll
  for (int ni = 0; ni < 4; ++ni) {
    const int col = cb * 128 + wcol + ni * 16 + lr;
    const float bv = bias[col];
    #pragma unroll
    for (int mi = 0; mi < 4; ++mi) {
      const int row0 = rb * 128 + wrow + mi * 16 + lg * 4;
      #pragma unroll
      for (int r = 0; r < 4; ++r) {
        float v = acc[mi][ni][r] + bv;
        if (relu) v = fmaxf(v, 0.f);
        C[(size_t)(row0 + r) * Ncols + col] = f2bf(v);
      }
    }
  }
}

// ---------------------------------------------------------------------------
// psi[j] = H3[j,:128] . W3 + b3
__global__ void k_l3(const short* __restrict__ H3, const float* __restrict__ W3,
                     const float* __restrict__ b3, float* __restrict__ psi) {
  const int j = blockIdx.x * 256 + threadIdx.x;
  if (j >= NP2) return;
  const short* hp = H3 + (size_t)j * 128;
  float acc = 0.f;
  #pragma unroll
  for (int i = 0; i < 128; i += 8) {
    bf16x8 h = *(const bf16x8*)(hp + i);
    #pragma unroll
    for (int u = 0; u < 8; ++u) acc += bf2f(h[u]) * W3[i + u];
  }
  psi[j] = acc + b3[0];
}

// ---------------------------------------------------------------------------
// a2raw[j] = (psi - sy2/norm)/(lambda*ln2) + log2(nu);  block max + psi sum
__global__ void k_a2(const float* __restrict__ psi, const float* __restrict__ sy2,
                     const float* __restrict__ nu, const float* __restrict__ scal,
                     float* __restrict__ a2raw, float* __restrict__ maxp,
                     float* __restrict__ sump) {
  const int j = blockIdx.x * 256 + threadIdx.x;
  const float invn = scal[1];
  float a = -1e30f, p = 0.f;
  if (j < NP2) {
    if (j < N_REAL) {
      p = psi[j];
      a = (p - sy2[j] * invn) * (1.0f / (LAMBD * LN2)) + log2f(nu[j]);
    }
    a2raw[j] = a;
  }
  __shared__ float redm[4], reds[4];
  #pragma unroll
  for (int m = 1; m < 64; m <<= 1) {
    a = fmaxf(a, __shfl_xor(a, m, 64));
    p += __shfl_xor(p, m, 64);
  }
  const int t = threadIdx.x;
  if ((t & 63) == 0) { redm[t >> 6] = a; reds[t >> 6] = p; }
  __syncthreads();
  if (t == 0) {
    maxp[blockIdx.x] = fmaxf(fmaxf(redm[0], redm[1]), fmaxf(redm[2], redm[3]));
    sump[blockIdx.x] = reds[0] + reds[1] + reds[2] + reds[3];
  }
}

__global__ void k_fin(const float* __restrict__ maxp, const float* __restrict__ sump,
                      float* __restrict__ scal, int nb) {
  const int t = threadIdx.x;  // 128
  __shared__ float ra[2], rs[2];
  float a = -1e30f, s = 0.f;
  for (int i = t; i < nb; i += 128) { a = fmaxf(a, maxp[i]); s += sump[i]; }
  #pragma unroll
  for (int m = 1; m < 64; m <<= 1) {
    a = fmaxf(a, __shfl_xor(a, m, 64));
    s += __shfl_xor(s, m, 64);
  }
  if ((t & 63) == 0) { ra[t >> 6] = a; rs[t >> 6] = s; }
  __syncthreads();
  if (t == 0) {
    scal[3] = fmaxf(ra[0], ra[1]);                 // A2 (global max, log2 domain)
    scal[4] = (rs[0] + rs[1]) / (float)N_REAL;     // mean(psi)
  }
}

__global__ void k_shift(float* __restrict__ a2s, const float* __restrict__ a2raw,
                        const float* __restrict__ scal) {
  const int j = blockIdx.x * 256 + threadIdx.x;
  if (j < NP2) a2s[j] = a2raw[j] - scal[3];
}

// ---------------------------------------------------------------------------
// Fused flash LSE, 256x256 tile, 8 waves (2Mx4N), BK=64, 8-phase-style
// schedule with counted vmcnt. 128KB dynamic LDS: [buf2][op2][16384 shorts].
__global__ __launch_bounds__(512, 2) void k_flash(const short* __restrict__ x_t,
                                                  const short* __restrict__ y_t,
                                                  const float* __restrict__ a2s,
                                                  const float* __restrict__ scal,
                                                  float* __restrict__ parts) {
  extern __shared__ short Lsh[];
  const int t = threadIdx.x;            // 0..511
  const int lane = t & 63, wave = t >> 6;
  const int lr = lane & 15, lg = lane >> 4;
  const int wr = wave >> 2, wc = wave & 3;
  const int rbt = blockIdx.y, split = blockIdx.x;
  const int ntiles = (NJT2 - split + NSPLIT2 - 1) / NSPLIT2;

  const float c1 = scal[2];

  const int t8 = t * 8;                 // per-lane source offset (shorts)
  const int w512 = wave * 512;          // wave-uniform LDS offset (shorts)
  const int lg2048 = lg * 2048;
  const int aoff = (wr * 128 + lr) * 8; // + mi*128
  const int boff = (wc * 64 + lr) * 8;  // + ni*128

  const short* Abase = x_t + ((size_t)(rbt * NKT) << 14);

  f32x4 acc[8][4];
  float sums[8][4];
  #pragma unroll
  for (int mi = 0; mi < 8; ++mi)
    #pragma unroll
    for (int ni = 0; ni < 4; ++ni) {
      acc[mi][ni] = (f32x4){0.f, 0.f, 0.f, 0.f};
      sums[mi][ni] = 0.f;
    }

  // stage item: op (0=A,1=B), half h, part p -> buf nb
  auto issue = [&](int nb, const short* An, const short* Bn, int h, int op, int p) {
    const short* s = (op ? Bn : An) + h * 8192 + p * 4096 + t8;
    short* d = Lsh + (size_t)((nb * 2 + op) * 16384 + h * 8192 + p * 4096 + w512);
    gload_lds16(s, d);
  };

  // prologue: tile (i=0, kt=0) -> buf 0, items in age order h0:{A0,A1,B0,B1}, h1:{...}
  {
    const short* An = Abase;
    const short* Bn = y_t + ((size_t)(split * NKT) << 14);
    #pragma unroll
    for (int h = 0; h < 2; ++h)
      #pragma unroll
      for (int op = 0; op < 2; ++op)
        #pragma unroll
        for (int p = 0; p < 2; ++p)
          issue(0, An, Bn, h, op, p);
  }
  asm volatile("s_waitcnt vmcnt(4)" ::: "memory");   // h0 items done; h1 in flight
  __builtin_amdgcn_s_barrier();
  __builtin_amdgcn_sched_barrier(0);

  for (int i = 0; i < ntiles; ++i) {
    for (int kt = 0; kt < NKT; ++kt) {
      const int buf = (i * NKT + kt) & 1;
      int in_ = i, ktn = kt + 1;
      if (ktn == NKT) { ktn = 0; ++in_; }
      const bool more = (in_ < ntiles);
      if (!more) { in_ = 0; ktn = 0; }
      const short* An = Abase + ((size_t)ktn << 14);
      const short* Bn = y_t + ((size_t)((size_t)(split + in_ * NSPLIT2) * NKT + ktn) << 14);
      const short* LA = Lsh + (size_t)((buf * 2) * 16384);
      const short* LB = Lsh + (size_t)((buf * 2 + 1) * 16384);
      const int nb = buf ^ 1;

      #pragma unroll
      for (int h = 0; h < 2; ++h) {
        const int pb = h * 8192 + lg2048;   // (h*4+lg)*256*8
        // ---- phase 0: mi 0..3 ----
        bf16x8 b0 = *(const bf16x8*)&LB[pb + boff];
        bf16x8 b1 = *(const bf16x8*)&LB[pb + boff + 128];
        bf16x8 b2 = *(const bf16x8*)&LB[pb + boff + 256];
        bf16x8 b3 = *(const bf16x8*)&LB[pb + boff + 384];
        bf16x8 a0 = *(const bf16x8*)&LA[pb + aoff];
        bf16x8 a1 = *(const bf16x8*)&LA[pb + aoff + 128];
        bf16x8 a2v = *(const bf16x8*)&LA[pb + aoff + 256];
        bf16x8 a3 = *(const bf16x8*)&LA[pb + aoff + 384];
        if (more) { issue(nb, An, Bn, h, 0, 0); issue(nb, An, Bn, h, 0, 1); }
        __builtin_amdgcn_s_setprio(1);
        #pragma unroll
        for (int ni = 0; ni < 4; ++ni) {
          bf16x8 bv = ni == 0 ? b0 : ni == 1 ? b1 : ni == 2 ? b2 : b3;
          acc[0][ni] = __builtin_amdgcn_mfma_f32_16x16x32_bf16(a0, bv, acc[0][ni], 0, 0, 0);
          acc[1][ni] = __builtin_amdgcn_mfma_f32_16x16x32_bf16(a1, bv, acc[1][ni], 0, 0, 0);
          acc[2][ni] = __builtin_amdgcn_mfma_f32_16x16x32_bf16(a2v, bv, acc[2][ni], 0, 0, 0);
          acc[3][ni] = __builtin_amdgcn_mfma_f32_16x16x32_bf16(a3, bv, acc[3][ni], 0, 0, 0);
        }
        __builtin_amdgcn_s_setprio(0);
        __builtin_amdgcn_s_barrier();
        __builtin_amdgcn_sched_barrier(0);
        // ---- phase 1: mi 4..7 ----
        bf16x8 a4 = *(const bf16x8*)&LA[pb + aoff + 512];
        bf16x8 a5 = *(const bf16x8*)&LA[pb + aoff + 640];
        bf16x8 a6 = *(const bf16x8*)&LA[pb + aoff + 768];
        bf16x8 a7 = *(const bf16x8*)&LA[pb + aoff + 896];
        if (more) { issue(nb, An, Bn, h, 1, 0); issue(nb, An, Bn, h, 1, 1); }
        __builtin_amdgcn_s_setprio(1);
        #pragma unroll
        for (int ni = 0; ni < 4; ++ni) {
          bf16x8 bv = ni == 0 ? b0 : ni == 1 ? b1 : ni == 2 ? b2 : b3;
          acc[4][ni] = __builtin_amdgcn_mfma_f32_16x16x32_bf16(a4, bv, acc[4][ni], 0, 0, 0);
          acc[5][ni] = __builtin_amdgcn_mfma_f32_16x16x32_bf16(a5, bv, acc[5][ni], 0, 0, 0);
          acc[6][ni] = __builtin_amdgcn_mfma_f32_16x16x32_bf16(a6, bv, acc[6][ni], 0, 0, 0);
          acc[7][ni] = __builtin_amdgcn_mfma_f32_16x16x32_bf16(a7, bv, acc[7][ni], 0, 0, 0);
        }
        __builtin_amdgcn_s_setprio(0);
        // boundary: counted wait — 4 newest (this half's prefetch) stay in flight
        if (more) asm volatile("s_waitcnt vmcnt(4)" ::: "memory");
        else      asm volatile("s_waitcnt vmcnt(0)" ::: "memory");
        __builtin_amdgcn_s_barrier();
        __builtin_amdgcn_sched_barrier(0);
      }
    }

    // ---- per-jt epilogue: sums += exp2(dot*c1 + a2s[col]) ----
    {
      const int jt = split + i * NSPLIT2;
      const float* ap = a2s + jt * 256 + wc * 64 + lr;
      const float av0 = ap[0];
      const float av1 = ap[16];
      const float av2 = ap[32];
      const float av3 = ap[48];
      // drain so a2s loads never pollute the staging vmcnt counting
      asm volatile("s_waitcnt vmcnt(0)" ::: "memory");
      #pragma unroll
      for (int mi = 0; mi < 8; ++mi)
        #pragma unroll
        for (int r = 0; r < 4; ++r) {
          sums[mi][r] += exp2f(acc[mi][0][r] * c1 + av0)
                       + exp2f(acc[mi][1][r] * c1 + av1)
                       + exp2f(acc[mi][2][r] * c1 + av2)
                       + exp2f(acc[mi][3][r] * c1 + av3);
          acc[mi][0][r] = 0.f; acc[mi][1][r] = 0.f;
          acc[mi][2][r] = 0.f; acc[mi][3][r] = 0.f;
        }
    }
  }

  // reduce each row's sum across the 16 lanes holding its columns
  #pragma unroll
  for (int mi = 0; mi < 8; ++mi)
    #pragma unroll
    for (int r = 0; r < 4; ++r) {
      float s = sums[mi][r];
      s += __shfl_xor(s, 1, 16);
      s += __shfl_xor(s, 2, 16);
      s += __shfl_xor(s, 4, 16);
      s += __shfl_xor(s, 8, 16);
      if (lr == 0) {
        const int row = rbt * 256 + wr * 128 + mi * 16 + lg * 4 + r;
        parts[(size_t)row * 64 + split * 4 + wc] = s;
      }
    }
}

// ---------------------------------------------------------------------------
__global__ void k_comb(const float* __restrict__ parts, const float* __restrict__ x2,
                       const float* __restrict__ scal, float* __restrict__ out) {
  const int b = blockIdx.x * 256 + threadIdx.x;
  if (b >= B_ROWS) return;
  float s = 0.f;
  #pragma unroll
  for (int i = 0; i < 64; ++i) s += parts[(size_t)b * 64 + i];
  out[b] = -(LAMBD * LN2) * (scal[3] + log2f(s)) + x2[b] * scal[1] + scal[4];
}

// ---------------------------------------------------------------------------
extern "C" void kernel_launch(void* const* d_in, const int* in_sizes, int n_in,
                              void* d_out, int out_size, void* d_ws, size_t ws_size,
                              hipStream_t stream) {
  const float* x  = (const float*)d_in[0];
  const float* y  = (const float*)d_in[1];
  const float* nu = (const float*)d_in[2];
  const float* W0 = (const float*)d_in[3];
  const float* b0 = (const float*)d_in[4];
  const float* W1 = (const float*)d_in[5];
  const float* b1 = (const float*)d_in[6];
  const float* W2 = (const float*)d_in[7];
  const float* b2 = (const float*)d_in[8];
  const float* W3 = (const float*)d_in[9];
  const float* b3 = (const float*)d_in[10];
  float* out = (float*)d_out;

  char* w = (char*)d_ws;
  auto alloc = [&](size_t bytes) {
    char* p = w;
    w += (bytes + 255) & ~(size_t)255;
    return p;
  };
  short* y_t   = (short*)alloc((size_t)NJT2 * NKT * 16384 * 2);          // 32.9 MB
  short* x_t   = (short*)alloc((size_t)(B_ROWS / 256) * NKT * 16384 * 2); // 6.7 MB
  short* W0b   = (short*)alloc((size_t)512 * DP2 * 2);
  short* W1b   = (short*)alloc((size_t)256 * 512 * 2);
  short* W2b   = (short*)alloc((size_t)128 * 256 * 2);
  short* H1    = (short*)alloc((size_t)NP2 * 512 * 2);
  short* H2    = (short*)alloc((size_t)NP2 * 256 * 2);
  short* H3    = (short*)alloc((size_t)NP2 * 128 * 2);
  float* sy2   = (float*)alloc((size_t)N_REAL * 4);
  float* x2    = (float*)alloc((size_t)B_ROWS * 4);
  float* psi   = (float*)alloc((size_t)NP2 * 4);
  float* a2raw = (float*)alloc((size_t)NP2 * 4);
  float* a2s   = (float*)alloc((size_t)NP2 * 4);
  float* maxp  = (float*)alloc(128 * 4);
  float* sump  = (float*)alloc(128 * 4);
  float* scal  = (float*)alloc(64 * 4);
  float* parts = (float*)alloc((size_t)B_ROWS * 64 * 4);

  // exact f32 row sumsq from original data
  k_sumsq<<<dim3(N_REAL), dim3(256), 0, stream>>>(y, sy2, D_IN / 4);
  k_sumsq<<<dim3(B_ROWS), dim3(256), 0, stream>>>(x, x2, D_IN / 4);
  k_norm<<<dim3(1), dim3(1024), 0, stream>>>(sy2, scal);

  // tiled bf16 operands + row-major weights (K padded to 832)
  k_convt<<<dim3(NJT2 * NKT), dim3(256), 0, stream>>>(y, y_t, N_REAL);
  k_convt<<<dim3((B_ROWS / 256) * NKT), dim3(256), 0, stream>>>(x, x_t, B_ROWS);
  k_convert<<<dim3(512), dim3(256), 0, stream>>>(W0, W0b, 512, D_IN, DP2);
  k_convert<<<dim3(256), dim3(256), 0, stream>>>(W1, W1b, 256, 512, 512);
  k_convert<<<dim3(128), dim3(256), 0, stream>>>(W2, W2b, 128, 256, 256);

  // MLP (layer 0 reads tiled y)
  k_gemm<true><<<dim3(4, NP2 / 128), dim3(256), 0, stream>>>(y_t, W0b, b0, H1, DP2, 512, 1);
  k_gemm<false><<<dim3(2, NP2 / 128), dim3(256), 0, stream>>>(H1, W1b, b1, H2, 512, 256, 1);
  k_gemm<false><<<dim3(1, NP2 / 128), dim3(256), 0, stream>>>(H2, W2b, b2, H3, 256, 128, 1);
  k_l3<<<dim3(NP2 / 256), dim3(256), 0, stream>>>(H3, W3, b3, psi);

  // a-vector + scalars
  const int nb_a2 = NP2 / 256;
  k_a2<<<dim3(nb_a2), dim3(256), 0, stream>>>(psi, sy2, nu, scal, a2raw, maxp, sump);
  k_fin<<<dim3(1), dim3(128), 0, stream>>>(maxp, sump, scal, nb_a2);
  k_shift<<<dim3(nb_a2), dim3(256), 0, stream>>>(a2s, a2raw, scal);

  // fused flash LSE (128KB dynamic LDS) + combine
  hipFuncSetAttribute((const void*)k_flash, hipFuncAttributeMaxDynamicSharedMemorySize, 131072);
  k_flash<<<dim3(NSPLIT2, B_ROWS / 256), dim3(512), 131072, stream>>>(x_t, y_t, a2s, scal, parts);
  k_comb<<<dim3(B_ROWS / 256), dim3(256), 0, stream>>>(parts, x2, scal, out);
}